// Round 7
// baseline (271.175 us; speedup 1.0000x reference)
//
#include <hip/hip_runtime.h>

// LSTM: B=16384 seqs, T=512, I=4, H=4, FC 4->1.
// Round 7: chain-latency attack. Model (fits R1-R6): wall/step = serial-chain
// latency (~310 cyc) + non-hideable issue. Chain was 2 nonlinearities deep
// (sigmoid(u_f) and tanh(c)), each mul->exp->add->rcp (2 serial trans, ~136
// cyc). Replace ALL nonlinearities with Pade[5/4] continued-fraction tanh:
//   tanh(x) ~ x(945+105t+t^2)/(945+420t+15t^2), t=x^2
// input clamp +-4.2, output clamp +-1 (max err ~1e-3, threshold 1.09e-2).
// One rcp per nonlinearity, zero exp: trans issue 160->80 cyc/step, chain
// nonlinearity 136->~92. sigmoid(x)=0.5+0.5*tanh(x/2): the 1/2 folded into
// weights; h_reg=2h with the 1/2 folded into W_hh columns and W_fc.
// Compute layout = R2 (best measured): 4 lanes/seq, 16 seqs/wave, DPP
// quad_perm h-broadcast, v2f gate pairs (i,f) and (g,o).

#define CH 8  // time-chunk for X prefetch

typedef float v2f __attribute__((ext_vector_type(2)));

__device__ __forceinline__ v2f pk_fma(v2f a, v2f b, v2f c) {
    return __builtin_elementwise_fma(a, b, c);
}

// DPP quad_perm lane-xor within aligned quads: xor1=0xB1, xor2=0x4E, xor3=0x1B
template <int CTRL>
__device__ __forceinline__ float quad_xor(float v) {
    int r = __builtin_amdgcn_mov_dpp(__float_as_int(v), CTRL, 0xF, 0xF, true);
    return __int_as_float(r);
}

// Pade[5/4] tanh, 2-wide. Input clamp +-4.2 (beyond which the rational
// overshoots 1 and the output clamp returns exactly +-1; err <= 4.5e-4
// there). Max err ~1.0e-3 near |x|~3.5.
__device__ __forceinline__ v2f pade_tanh2(v2f u) {
    const float HI = 4.2f;
    u = __builtin_elementwise_min(
            __builtin_elementwise_max(u, (v2f){-HI, -HI}), (v2f){HI, HI});
    v2f t  = u * u;
    v2f t2 = t * t;
    v2f q  = pk_fma(t, (v2f){105.0f, 105.0f}, (v2f){945.0f, 945.0f}) + t2;
    v2f num = u * q;
    v2f den = pk_fma(t2, (v2f){15.0f, 15.0f},
                     pk_fma(t, (v2f){420.0f, 420.0f}, (v2f){945.0f, 945.0f}));
    v2f r = (v2f){__builtin_amdgcn_rcpf(den.x), __builtin_amdgcn_rcpf(den.y)};
    v2f T = num * r;
    return __builtin_elementwise_min(
            __builtin_elementwise_max(T, (v2f){-1.0f, -1.0f}), (v2f){1.0f, 1.0f});
}

__device__ __forceinline__ float pade_tanh1(float u) {
    const float HI = 4.2f;
    u = fminf(fmaxf(u, -HI), HI);
    float t  = u * u;
    float t2 = t * t;
    float num = u * (fmaf(t, 105.0f, 945.0f) + t2);
    float den = fmaf(t2, 15.0f, fmaf(t, 420.0f, 945.0f));
    float T = num * __builtin_amdgcn_rcpf(den);
    return fminf(fmaxf(T, -1.0f), 1.0f);
}

__global__ __launch_bounds__(256) void lstm_h4_kernel(
    const float* __restrict__ X,
    const float* __restrict__ W_ih,
    const float* __restrict__ W_hh,
    const float* __restrict__ b_ih,
    const float* __restrict__ b_hh,
    const float* __restrict__ W_fc,
    const float* __restrict__ b_fc,
    float* __restrict__ out,
    int B, int T)
{
    int gid = blockIdx.x * blockDim.x + threadIdx.x;
    int b = gid >> 2;       // sequence index
    int j = gid & 3;        // hidden unit index
    if (b >= B) return;

    // Gate rows (PyTorch): 0-3=i, 4-7=f, 8-11=g, 12-15=o.
    // Pair 0 = (i_j, f_j); pair 1 = (g_j, o_j).
    // Scales: sigmoid gates (i,f,o) compute tanh(u/2) -> W,b * 0.5.
    // h register holds 2h -> W_hh columns get an extra 0.5.
    v2f wih0[4], wih1[4], whh0[4], whh1[4], bias0, bias1;
    {
        const float sc[4] = {0.5f, 0.5f, 1.0f, 0.5f};   // i, f, g, o
        int rI = 0 * 4 + j, rF = 1 * 4 + j, rG = 2 * 4 + j, rO = 3 * 4 + j;
#pragma unroll
        for (int k = 0; k < 4; ++k) {
            wih0[k] = (v2f){sc[0] * W_ih[rI * 4 + k], sc[1] * W_ih[rF * 4 + k]};
            wih1[k] = (v2f){sc[2] * W_ih[rG * 4 + k], sc[3] * W_ih[rO * 4 + k]};
            int kc = j ^ k;            // h from quad lane j^k is h_{j^k}
            whh0[k] = (v2f){0.5f * sc[0] * W_hh[rI * 4 + kc],
                            0.5f * sc[1] * W_hh[rF * 4 + kc]};
            whh1[k] = (v2f){0.5f * sc[2] * W_hh[rG * 4 + kc],
                            0.5f * sc[3] * W_hh[rO * 4 + kc]};
        }
        bias0 = (v2f){sc[0] * (b_ih[rI] + b_hh[rI]), sc[1] * (b_ih[rF] + b_hh[rF])};
        bias1 = (v2f){sc[2] * (b_ih[rG] + b_hh[rG]), sc[3] * (b_ih[rO] + b_hh[rO])};
    }

    const float4* __restrict__ xp = (const float4*)X + (size_t)b * T;

    float h = 0.0f, c = 0.0f;   // h register = 2 * true h

    float4 cur[CH], nxt[CH];
#pragma unroll
    for (int i = 0; i < CH; ++i) cur[i] = xp[i];

    for (int tc = 0; tc < T; tc += CH) {
        if (tc + CH < T) {
#pragma unroll
            for (int i = 0; i < CH; ++i) nxt[i] = xp[tc + CH + i];
        }
#pragma unroll
        for (int i = 0; i < CH; ++i) {
            float4 x = cur[i];
            // x path (independent of recurrence)
            v2f p0 = bias0, p1 = bias1;
            p0 = pk_fma(wih0[0], (v2f){x.x, x.x}, p0);
            p1 = pk_fma(wih1[0], (v2f){x.x, x.x}, p1);
            p0 = pk_fma(wih0[1], (v2f){x.y, x.y}, p0);
            p1 = pk_fma(wih1[1], (v2f){x.y, x.y}, p1);
            p0 = pk_fma(wih0[2], (v2f){x.z, x.z}, p0);
            p1 = pk_fma(wih1[2], (v2f){x.z, x.z}, p1);
            p0 = pk_fma(wih0[3], (v2f){x.w, x.w}, p0);
            p1 = pk_fma(wih1[3], (v2f){x.w, x.w}, p1);
            // h path (quad broadcast + depth-3 tree)
            float h1 = quad_xor<0xB1>(h);
            float h2 = quad_xor<0x4E>(h);
            float h3 = quad_xor<0x1B>(h);
            v2f hb0 = (v2f){h,  h},  hb1 = (v2f){h1, h1};
            v2f hb2 = (v2f){h2, h2}, hb3 = (v2f){h3, h3};
            v2f u0a = pk_fma(whh0[0], hb0, p0);
            v2f u0b = pk_fma(whh0[2], hb2, whh0[3] * hb3);
            v2f u1a = pk_fma(whh1[0], hb0, p1);
            v2f u1b = pk_fma(whh1[2], hb2, whh1[3] * hb3);
            v2f u0 = pk_fma(whh0[1], hb1, u0a) + u0b;   // (u_i/2, u_f/2)
            v2f u1 = pk_fma(whh1[1], hb1, u1a) + u1b;   // (u_g,   u_o/2)

            // nonlinearities: Pade tanh only (1 rcp each, no exp)
            v2f T0 = pade_tanh2(u0);   // (Ti, Tf)
            v2f T1 = pade_tanh2(u1);   // (Tg, To)

            // c = 0.5(1+Tf)c + 0.5(1+Ti)Tg
            float halfB = 0.5f * fmaf(T0.x, T1.x, T1.x);   // off-chain
            float A     = fmaf(T0.y, c, c);                // chain
            c = fmaf(0.5f, A, halfB);

            // h_reg = 2h = (1+To)*tanh(c)
            float Tc = pade_tanh1(c);
            h = fmaf(T1.y, Tc, Tc);
        }
#pragma unroll
        for (int i = 0; i < CH; ++i) cur[i] = nxt[i];
    }

    // out[b] = sum_j h_j*W_fc[j] + b_fc ; h_reg=2h -> use 0.5*W_fc
    float partial = h * (0.5f * W_fc[j]);
    partial += quad_xor<0xB1>(partial);
    partial += quad_xor<0x4E>(partial);
    if (j == 0) out[b] = partial + b_fc[0];
}

extern "C" void kernel_launch(void* const* d_in, const int* in_sizes, int n_in,
                              void* d_out, int out_size, void* d_ws, size_t ws_size,
                              hipStream_t stream) {
    const float* X    = (const float*)d_in[0];
    const float* W_ih = (const float*)d_in[1];
    const float* W_hh = (const float*)d_in[2];
    const float* b_ih = (const float*)d_in[3];
    const float* b_hh = (const float*)d_in[4];
    const float* W_fc = (const float*)d_in[5];
    const float* b_fc = (const float*)d_in[6];
    float* out = (float*)d_out;

    int B = out_size;                       // 16384
    int T = in_sizes[0] / (B * 4);          // 512 (I=4)

    int threads = B * 4;
    dim3 block(256);
    dim3 grid((threads + 255) / 256);
    lstm_h4_kernel<<<grid, block, 0, stream>>>(X, W_ih, W_hh, b_ih, b_hh,
                                               W_fc, b_fc, out, B, T);
}